// Round 1
// baseline (1860.611 us; speedup 1.0000x reference)
//
#include <hip/hip_runtime.h>
#include <hip/hip_cooperative_groups.h>

namespace cg = cooperative_groups;

#define B_    4
#define S_    512
#define D_    64
#define H_    8
#define DH_   8
#define DFF_  256
#define N_    2048          // B_*S_
#define GWG   256           // workgroups (1 per CU)
#define TPB   256
#define RPW   8             // rows per workgroup
#define NSTEPS 4
#define DTs   0.25f

// RKF56 (Fehlberg) tableau
__constant__ float A_tab[6][5] = {
    {0.f, 0.f, 0.f, 0.f, 0.f},
    {0.25f, 0.f, 0.f, 0.f, 0.f},
    {3.0f/32.0f, 9.0f/32.0f, 0.f, 0.f, 0.f},
    {1932.0f/2197.0f, -7200.0f/2197.0f, 7296.0f/2197.0f, 0.f, 0.f},
    {439.0f/216.0f, -8.0f, 3680.0f/513.0f, -845.0f/4104.0f, 0.f},
    {-8.0f/27.0f, 2.0f, -3544.0f/2565.0f, 1859.0f/4104.0f, -11.0f/40.0f}};
__constant__ float B_tab[6] = {16.0f/135.0f, 0.0f, 6656.0f/12825.0f,
                               28561.0f/56430.0f, -9.0f/50.0f, 2.0f/55.0f};

__global__ __launch_bounds__(TPB, 1) void ode_enc_kernel(
    const float* __restrict__ x,
    const float* __restrict__ Wq, const float* __restrict__ bq,
    const float* __restrict__ Wk, const float* __restrict__ bk,
    const float* __restrict__ Wv, const float* __restrict__ bv,
    const float* __restrict__ Wo, const float* __restrict__ bo,
    const float* __restrict__ W1, const float* __restrict__ b1,
    const float* __restrict__ W2, const float* __restrict__ b2,
    float* __restrict__ out,
    float* __restrict__ g_y,    // [N_*D_]
    float* __restrict__ g_k,    // [2][N_*D_] ping-pong K projection
    float* __restrict__ g_v,    // [2][N_*D_] ping-pong V projection
    float* __restrict__ g_ks)   // [5][N_*D_] RK slopes k1..k5
{
    cg::grid_group grid = cg::this_grid();
    const int wg   = blockIdx.x;
    const int tid  = threadIdx.x;
    const int row0 = wg * RPW;          // first global row owned by this wg
    const int bidx = wg >> 6;           // batch index (64 wgs per batch)
    const int krow0 = bidx * S_;        // first key row of this batch

    __shared__ float sy[RPW][D_];       // ystage (persists P1 -> P2b)
    __shared__ float sq[RPW][D_];       // Q projection (persists P1 -> P2a)
    __shared__ float satt[RPW][D_];     // attention output (pre-Wo)
    __shared__ float so[RPW][D_];       // att after Wo+bo
    __shared__ float sh[RPW][D_];       // ffn input y_stage + att
    __shared__ float st[RPW][DFF_];     // relu(h@W1+b1)
    __shared__ float red[RPW][DH_][H_][9];  // raw acc partials [q][d][h][ks pad 9]
    __shared__ float sml[RPW][H_][8][2];    // (m,l) per (q,h,ks)
    __shared__ float swn[RPW][H_][9];       // merged weight/L per (q,h,ks)

    // ---- init: copy x -> y (own rows only; row-local) ----
    for (int i = tid; i < RPW * D_; i += TPB)
        g_y[row0 * D_ + i] = x[row0 * D_ + i];
    __syncthreads();

    for (int step = 0; step < NSTEPS; ++step) {
        for (int stage = 0; stage < 6; ++stage) {
            const int t   = step * 6 + stage;
            const int buf = t & 1;

            // ================= P1: stage input + QKV projection ============
            {
                const int c  = tid & 63;
                const int rr = tid >> 6;   // 0..3
                #pragma unroll
                for (int p = 0; p < 2; ++p) {
                    const int r  = rr + 4 * p;
                    const int rg = row0 + r;
                    float acc = g_y[rg * D_ + c];
                    for (int j = 0; j < stage; ++j) {
                        const float aj = A_tab[stage][j];
                        acc += (DTs * aj) * g_ks[(j * N_ + rg) * D_ + c];
                    }
                    sy[r][c] = acc;
                }
                __syncthreads();

                float aq0 = 0.f, aq1 = 0.f, ak0 = 0.f, ak1 = 0.f, av0 = 0.f, av1 = 0.f;
                const int r0 = rr, r1 = rr + 4;
                #pragma unroll 4
                for (int d = 0; d < D_; ++d) {
                    const float s0 = sy[r0][d], s1 = sy[r1][d];
                    const float wq = Wq[d * D_ + c];
                    const float wk = Wk[d * D_ + c];
                    const float wv = Wv[d * D_ + c];
                    aq0 = fmaf(s0, wq, aq0); aq1 = fmaf(s1, wq, aq1);
                    ak0 = fmaf(s0, wk, ak0); ak1 = fmaf(s1, wk, ak1);
                    av0 = fmaf(s0, wv, av0); av1 = fmaf(s1, wv, av1);
                }
                const float bqc = bq[c], bkc = bk[c], bvc = bv[c];
                sq[r0][c] = aq0 + bqc;
                sq[r1][c] = aq1 + bqc;
                g_k[(buf * N_ + row0 + r0) * D_ + c] = ak0 + bkc;
                g_k[(buf * N_ + row0 + r1) * D_ + c] = ak1 + bkc;
                g_v[(buf * N_ + row0 + r0) * D_ + c] = av0 + bvc;
                g_v[(buf * N_ + row0 + r1) * D_ + c] = av1 + bvc;
            }

            grid.sync();   // K/V of all rows of this batch must be visible

            // ================= P2a: attention =============================
            {
                const int q4 = tid >> 6;        // wave id -> rows 2*q4, 2*q4+1
                const int h  = (tid >> 3) & 7;
                const int ks = tid & 7;         // key slice: 64 keys
                const int qr0 = 2 * q4, qr1 = qr0 + 1;

                const float SC = 1.4426950408889634f * 0.35355339059327373f; // log2(e)/sqrt(8)
                float qv0[8], qv1[8];
                #pragma unroll
                for (int d = 0; d < 8; ++d) {
                    qv0[d] = sq[qr0][h * 8 + d] * SC;
                    qv1[d] = sq[qr1][h * 8 + d] * SC;
                }
                float m0 = -1e30f, m1 = -1e30f, l0 = 0.f, l1 = 0.f;
                float acc0[8], acc1[8];
                #pragma unroll
                for (int d = 0; d < 8; ++d) { acc0[d] = 0.f; acc1[d] = 0.f; }

                const float* kbase = g_k + (buf * N_ + krow0) * D_;
                const float* vbase = g_v + (buf * N_ + krow0) * D_;

                #pragma unroll 2
                for (int i = 0; i < 64; ++i) {
                    const int k = ks * 64 + i;
                    const float4 kA = *(const float4*)(kbase + k * D_ + h * 8);
                    const float4 kB = *(const float4*)(kbase + k * D_ + h * 8 + 4);
                    const float4 vA = *(const float4*)(vbase + k * D_ + h * 8);
                    const float4 vB = *(const float4*)(vbase + k * D_ + h * 8 + 4);
                    const float kk[8] = {kA.x, kA.y, kA.z, kA.w, kB.x, kB.y, kB.z, kB.w};
                    const float vv[8] = {vA.x, vA.y, vA.z, vA.w, vB.x, vB.y, vB.z, vB.w};

                    float s0 = 0.f, s1 = 0.f;
                    #pragma unroll
                    for (int d = 0; d < 8; ++d) {
                        s0 = fmaf(qv0[d], kk[d], s0);
                        s1 = fmaf(qv1[d], kk[d], s1);
                    }
                    // deferred-rescale online softmax (exp2 domain, THR=8)
                    if (s0 > m0 + 8.f) {
                        const float al = exp2f(m0 - s0);
                        m0 = s0; l0 *= al;
                        #pragma unroll
                        for (int d = 0; d < 8; ++d) acc0[d] *= al;
                    }
                    const float p0 = exp2f(s0 - m0);
                    l0 += p0;
                    #pragma unroll
                    for (int d = 0; d < 8; ++d) acc0[d] = fmaf(p0, vv[d], acc0[d]);

                    if (s1 > m1 + 8.f) {
                        const float al = exp2f(m1 - s1);
                        m1 = s1; l1 *= al;
                        #pragma unroll
                        for (int d = 0; d < 8; ++d) acc1[d] *= al;
                    }
                    const float p1 = exp2f(s1 - m1);
                    l1 += p1;
                    #pragma unroll
                    for (int d = 0; d < 8; ++d) acc1[d] = fmaf(p1, vv[d], acc1[d]);
                }

                sml[qr0][h][ks][0] = m0; sml[qr0][h][ks][1] = l0;
                sml[qr1][h][ks][0] = m1; sml[qr1][h][ks][1] = l1;
                #pragma unroll
                for (int d = 0; d < 8; ++d) {
                    red[qr0][d][h][ks] = acc0[d];
                    red[qr1][d][h][ks] = acc1[d];
                }
            }
            __syncthreads();

            // stage A: merged softmax weights per (q,h)
            if (tid < 64) {
                const int q = tid >> 3, hh = tid & 7;
                float mv[8], lv[8], M = -1e30f;
                #pragma unroll
                for (int i = 0; i < 8; ++i) {
                    mv[i] = sml[q][hh][i][0];
                    lv[i] = sml[q][hh][i][1];
                    M = fmaxf(M, mv[i]);
                }
                float L = 0.f, w[8];
                #pragma unroll
                for (int i = 0; i < 8; ++i) { w[i] = exp2f(mv[i] - M); L = fmaf(lv[i], w[i], L); }
                const float inv = 1.0f / L;
                #pragma unroll
                for (int i = 0; i < 8; ++i) swn[q][hh][i] = w[i] * inv;
            }
            __syncthreads();

            // stage B: combine partials -> satt
            for (int o = tid; o < RPW * D_; o += TPB) {
                const int q = o >> 6, hd = o & 63;
                const int hh = hd >> 3, d = hd & 7;
                float s = 0.f;
                #pragma unroll
                for (int i = 0; i < 8; ++i) s = fmaf(red[q][d][hh][i], swn[q][hh][i], s);
                satt[q][hd] = s;
            }
            __syncthreads();

            // ================= P2b: Wo proj + FFN + k_i ===================
            {
                const int c  = tid & 63;
                const int rr = tid >> 6;
                float a0 = 0.f, a1 = 0.f;
                #pragma unroll 4
                for (int d = 0; d < D_; ++d) {
                    const float wo = Wo[d * D_ + c];
                    a0 = fmaf(satt[rr][d], wo, a0);
                    a1 = fmaf(satt[rr + 4][d], wo, a1);
                }
                const float boc = bo[c];
                a0 += boc; a1 += boc;
                so[rr][c] = a0;       so[rr + 4][c] = a1;
                sh[rr][c] = sy[rr][c] + a0;
                sh[rr + 4][c] = sy[rr + 4][c] + a1;
            }
            __syncthreads();

            // FFN1: st = relu(sh @ W1 + b1), thread = one of 256 cols
            {
                const int c2 = tid;
                float acc[8];
                #pragma unroll
                for (int r = 0; r < 8; ++r) acc[r] = 0.f;
                #pragma unroll 2
                for (int d = 0; d < D_; ++d) {
                    const float w1 = W1[d * DFF_ + c2];
                    #pragma unroll
                    for (int r = 0; r < 8; ++r) acc[r] = fmaf(sh[r][d], w1, acc[r]);
                }
                const float b1c = b1[c2];
                #pragma unroll
                for (int r = 0; r < 8; ++r) st[r][c2] = fmaxf(acc[r] + b1c, 0.f);
            }
            __syncthreads();

            // FFN2 + k_i (+ y update / output at stage 5)
            {
                const int c  = tid & 63;
                const int rr = tid >> 6;
                float f0 = 0.f, f1 = 0.f;
                #pragma unroll 4
                for (int c2 = 0; c2 < DFF_; ++c2) {
                    const float w2 = W2[c2 * D_ + c];
                    f0 = fmaf(st[rr][c2], w2, f0);
                    f1 = fmaf(st[rr + 4][c2], w2, f1);
                }
                const float b2c = b2[c];
                const float k0v = so[rr][c] + f0 + b2c;       // dyn = att + ffn
                const float k1v = so[rr + 4][c] + f1 + b2c;
                const int rg0 = row0 + rr, rg1 = row0 + rr + 4;

                if (stage < 5) {
                    g_ks[(stage * N_ + rg0) * D_ + c] = k0v;
                    g_ks[(stage * N_ + rg1) * D_ + c] = k1v;
                } else {
                    const float Bt0 = B_tab[0], Bt2 = B_tab[2], Bt3 = B_tab[3],
                                Bt4 = B_tab[4], Bt5 = B_tab[5];
                    float yn0 = Bt0 * g_ks[(0 * N_ + rg0) * D_ + c];
                    yn0 = fmaf(Bt2, g_ks[(2 * N_ + rg0) * D_ + c], yn0);
                    yn0 = fmaf(Bt3, g_ks[(3 * N_ + rg0) * D_ + c], yn0);
                    yn0 = fmaf(Bt4, g_ks[(4 * N_ + rg0) * D_ + c], yn0);
                    yn0 = fmaf(Bt5, k0v, yn0);
                    yn0 = fmaf(DTs, yn0, g_y[rg0 * D_ + c]);

                    float yn1 = Bt0 * g_ks[(0 * N_ + rg1) * D_ + c];
                    yn1 = fmaf(Bt2, g_ks[(2 * N_ + rg1) * D_ + c], yn1);
                    yn1 = fmaf(Bt3, g_ks[(3 * N_ + rg1) * D_ + c], yn1);
                    yn1 = fmaf(Bt4, g_ks[(4 * N_ + rg1) * D_ + c], yn1);
                    yn1 = fmaf(Bt5, k1v, yn1);
                    yn1 = fmaf(DTs, yn1, g_y[rg1 * D_ + c]);

                    if (step < NSTEPS - 1) {
                        g_y[rg0 * D_ + c] = yn0;
                        g_y[rg1 * D_ + c] = yn1;
                    } else {
                        out[rg0 * D_ + c] = yn0;
                        out[rg1 * D_ + c] = yn1;
                    }
                }
            }
            // No block/grid barrier needed here: next P1 only touches row-local
            // data written by the SAME thread (g_ks/g_y mapping is identical),
            // and its first __syncthreads orders the sy rewrite.
        }
    }
}

extern "C" void kernel_launch(void* const* d_in, const int* in_sizes, int n_in,
                              void* d_out, int out_size, void* d_ws, size_t ws_size,
                              hipStream_t stream) {
    const float* x  = (const float*)d_in[0];
    // d_in[1] = mask: additive per-(b,q)-row constant over the key axis ->
    // softmax-invariant -> mathematically a no-op. Ignored.
    const float* Wq = (const float*)d_in[2];
    const float* bq = (const float*)d_in[3];
    const float* Wk = (const float*)d_in[4];
    const float* bk = (const float*)d_in[5];
    const float* Wv = (const float*)d_in[6];
    const float* bv = (const float*)d_in[7];
    const float* Wo = (const float*)d_in[8];
    const float* bo = (const float*)d_in[9];
    const float* W1 = (const float*)d_in[10];
    const float* b1 = (const float*)d_in[11];
    const float* W2 = (const float*)d_in[12];
    const float* b2 = (const float*)d_in[13];
    float* out  = (float*)d_out;

    float* base = (float*)d_ws;
    float* g_y  = base;                    // N_*D_
    float* g_k  = g_y + N_ * D_;           // 2*N_*D_
    float* g_v  = g_k + 2 * N_ * D_;       // 2*N_*D_
    float* g_ks = g_v + 2 * N_ * D_;       // 5*N_*D_   (total 5.24 MB)

    void* args[] = {
        (void*)&x,
        (void*)&Wq, (void*)&bq, (void*)&Wk, (void*)&bk,
        (void*)&Wv, (void*)&bv, (void*)&Wo, (void*)&bo,
        (void*)&W1, (void*)&b1, (void*)&W2, (void*)&b2,
        (void*)&out,
        (void*)&g_y, (void*)&g_k, (void*)&g_v, (void*)&g_ks,
    };
    hipLaunchCooperativeKernel((void*)ode_enc_kernel, dim3(GWG), dim3(TPB),
                               args, 0, stream);
}

// Round 3
// 1467.555 us; speedup vs baseline: 1.2678x; 1.2678x over previous
//
#include <hip/hip_runtime.h>
#include <hip/hip_cooperative_groups.h>

namespace cg = cooperative_groups;

#define B_    4
#define S_    512
#define D_    64
#define DFF_  256
#define N_    2048          // B_*S_
#define GWG   256           // 1 block per CU (cooperative-safe, proven R1)
#define TPB   512           // 8 waves/block = 2 waves/SIMD
#define RPW   8             // rows per workgroup
#define NSTEPS 4
#define DTs   0.25f

__constant__ float A_tab[6][5] = {
    {0.f, 0.f, 0.f, 0.f, 0.f},
    {0.25f, 0.f, 0.f, 0.f, 0.f},
    {3.0f/32.0f, 9.0f/32.0f, 0.f, 0.f, 0.f},
    {1932.0f/2197.0f, -7200.0f/2197.0f, 7296.0f/2197.0f, 0.f, 0.f},
    {439.0f/216.0f, -8.0f, 3680.0f/513.0f, -845.0f/4104.0f, 0.f},
    {-8.0f/27.0f, 2.0f, -3544.0f/2565.0f, 1859.0f/4104.0f, -11.0f/40.0f}};
__constant__ float B_tab[6] = {16.0f/135.0f, 0.0f, 6656.0f/12825.0f,
                               28561.0f/56430.0f, -9.0f/50.0f, 2.0f/55.0f};

__global__ __launch_bounds__(TPB, 1) void ode_enc_kernel(
    const float* __restrict__ x,
    const float* __restrict__ Wq, const float* __restrict__ bq,
    const float* __restrict__ Wk, const float* __restrict__ bk,
    const float* __restrict__ Wv, const float* __restrict__ bv,
    const float* __restrict__ Wo, const float* __restrict__ bo,
    const float* __restrict__ W1, const float* __restrict__ b1,
    const float* __restrict__ W2, const float* __restrict__ b2,
    float* __restrict__ out,
    float* __restrict__ g_k,    // [2][N_*D_] ping-pong K
    float* __restrict__ g_v)    // [2][N_*D_] ping-pong V
{
    cg::grid_group grid = cg::this_grid();
    const int wg   = blockIdx.x;
    const int tid  = threadIdx.x;
    const int lane = tid & 63;
    const int wv   = tid >> 6;            // wave id 0..7
    const int row0  = wg * RPW;
    const int krow0 = (wg >> 6) * S_;     // batch base (64 blocks per batch)

    // thread's "own" element for combine phases: (row wv, col lane)
    const int r_own = wv;
    const int c_own = lane;

    __shared__ float sy[RPW][D_];         // stage input (broadcast reads)
    __shared__ float satt[RPW][D_];       // attention output
    __shared__ float sh[RPW][D_];         // FFN input
    __shared__ float st[RPW][DFF_];       // relu(h@W1+b1)
    __shared__ float kst[5][RPW][D_];     // RK slopes (same-thread access only)
    __shared__ float U[8192];             // union: QKV partials | K/V tiles | redo | red1 | red2

    // per-thread state
    float ys_reg = x[(row0 + r_own) * D_ + c_own];
    const float bq_r = bq[c_own], bk_r = bk[c_own], bv_r = bv[c_own];
    const float bo_r = bo[c_own], b2_r = b2[c_own];
    const float b1_r = b1[tid & 255];

    for (int step = 0; step < NSTEPS; ++step) {
        for (int stage = 0; stage < 6; ++stage) {
            const int buf = (step * 6 + stage) & 1;

            // ---------- P1: RK stage input ----------
            float stin = ys_reg;
            #pragma unroll
            for (int j = 0; j < 5; ++j)
                if (j < stage) stin = fmaf(DTs * A_tab[stage][j], kst[j][r_own][c_own], stin);
            sy[r_own][c_own] = stin;
            __syncthreads();   // SYNC_A

            // ---------- QKV compute: waves 0..5 = (mat, d-half) ----------
            if (wv < 6) {
                const int mat = wv >> 1, p = wv & 1;
                const float* Wm = (mat == 0) ? Wq : (mat == 1) ? Wk : Wv;
                float acc[8];
                #pragma unroll
                for (int r = 0; r < 8; ++r) acc[r] = 0.f;
                #pragma unroll
                for (int i4 = 0; i4 < 8; ++i4) {
                    const int dd0 = p * 32 + i4 * 4;
                    const float w0 = Wm[(dd0 + 0) * D_ + lane];
                    const float w1 = Wm[(dd0 + 1) * D_ + lane];
                    const float w2 = Wm[(dd0 + 2) * D_ + lane];
                    const float w3 = Wm[(dd0 + 3) * D_ + lane];
                    #pragma unroll
                    for (int r = 0; r < 8; ++r) {
                        const float4 s4 = *(const float4*)&sy[r][dd0];
                        acc[r] = fmaf(s4.x, w0, fmaf(s4.y, w1, fmaf(s4.z, w2, fmaf(s4.w, w3, acc[r]))));
                    }
                }
                #pragma unroll
                for (int r = 0; r < 8; ++r) U[(wv * 8 + r) * 64 + lane] = acc[r];
            }
            __syncthreads();   // SYNC_B

            // ---------- QKV combine: thread (r_own, c_own) ----------
            float sqreg;
            {
                const float qv = U[(0 * 8 + r_own) * 64 + c_own] + U[(1 * 8 + r_own) * 64 + c_own] + bq_r;
                const float kv = U[(2 * 8 + r_own) * 64 + c_own] + U[(3 * 8 + r_own) * 64 + c_own] + bk_r;
                const float vv = U[(4 * 8 + r_own) * 64 + c_own] + U[(5 * 8 + r_own) * 64 + c_own] + bv_r;
                sqreg = qv;
                const size_t kidx = ((size_t)buf * N_ + row0 + r_own) * D_ + c_own;
                g_k[kidx] = kv;
                g_v[kidx] = vv;
            }
            grid.sync();       // K/V of the whole batch visible

            // ---------- attention: wave wv = q-row wv ----------
            {
                const int h  = lane & 7;       // head
                const int ks = lane >> 3;      // key-slot within tile
                const float SC = 0.51006702f;  // log2(e)/sqrt(8)
                float qv[8];
                #pragma unroll
                for (int d = 0; d < 8; ++d) qv[d] = __shfl(sqreg, h * 8 + d) * SC;

                int cbase[8];
                #pragma unroll
                for (int d = 0; d < 8; ++d) cbase[d] = h * 8 + (d ^ ks);

                float m = -1e30f, l = 0.f;
                float acc8[8];
                #pragma unroll
                for (int d = 0; d < 8; ++d) acc8[d] = 0.f;

                // staging geometry (same for every tile)
                const int jrow = (lane & 7) * 8 + wv;   // row this thread stages
                const int c0   = (lane >> 3) * 8;
                const int sw   = lane & 7;              // = jrow>>3
                const int wbase = jrow * 64 + c0;

                for (int tile = 0; tile < 8; ++tile) {
                    // stage K/V tile (64 keys x 64 dims), XOR-swizzled
                    const size_t gidx = ((size_t)buf * N_ + krow0 + tile * 64 + jrow) * D_ + c0;
                    const float4 ka = *(const float4*)(g_k + gidx);
                    const float4 kb = *(const float4*)(g_k + gidx + 4);
                    const float4 va = *(const float4*)(g_v + gidx);
                    const float4 vb = *(const float4*)(g_v + gidx + 4);
                    U[wbase + (0 ^ sw)] = ka.x; U[wbase + (1 ^ sw)] = ka.y;
                    U[wbase + (2 ^ sw)] = ka.z; U[wbase + (3 ^ sw)] = ka.w;
                    U[wbase + (4 ^ sw)] = kb.x; U[wbase + (5 ^ sw)] = kb.y;
                    U[wbase + (6 ^ sw)] = kb.z; U[wbase + (7 ^ sw)] = kb.w;
                    U[4096 + wbase + (0 ^ sw)] = va.x; U[4096 + wbase + (1 ^ sw)] = va.y;
                    U[4096 + wbase + (2 ^ sw)] = va.z; U[4096 + wbase + (3 ^ sw)] = va.w;
                    U[4096 + wbase + (4 ^ sw)] = vb.x; U[4096 + wbase + (5 ^ sw)] = vb.y;
                    U[4096 + wbase + (6 ^ sw)] = vb.z; U[4096 + wbase + (7 ^ sw)] = vb.w;
                    __syncthreads();   // SYNC_T1

                    #pragma unroll
                    for (int i = 0; i < 8; ++i) {
                        const int jb = (ks * 8 + i) * 64;
                        float kk[8], vvv[8];
                        #pragma unroll
                        for (int d = 0; d < 8; ++d) kk[d] = U[jb + cbase[d]];
                        #pragma unroll
                        for (int d = 0; d < 8; ++d) vvv[d] = U[4096 + jb + cbase[d]];
                        float s = fmaf(qv[0], kk[0], fmaf(qv[1], kk[1], fmaf(qv[2], kk[2],
                                  fmaf(qv[3], kk[3], fmaf(qv[4], kk[4], fmaf(qv[5], kk[5],
                                  fmaf(qv[6], kk[6], qv[7] * kk[7])))))));
                        if (s > m + 8.f) {            // deferred-rescale (T13)
                            const float al = exp2f(m - s);
                            m = s; l *= al;
                            #pragma unroll
                            for (int d = 0; d < 8; ++d) acc8[d] *= al;
                        }
                        const float p = exp2f(s - m);
                        l += p;
                        #pragma unroll
                        for (int d = 0; d < 8; ++d) acc8[d] = fmaf(p, vvv[d], acc8[d]);
                    }
                    __syncthreads();   // SYNC_T2 (tile buffer reusable)
                }

                // merge across ks-lanes (lane bits 3..5 -> offsets 8,16,32)
                #pragma unroll
                for (int off = 8; off < 64; off <<= 1) {
                    const float mo = __shfl_xor(m, off);
                    const float lo = __shfl_xor(l, off);
                    float ab[8];
                    #pragma unroll
                    for (int d = 0; d < 8; ++d) ab[d] = __shfl_xor(acc8[d], off);
                    const float M  = fmaxf(m, mo);
                    const float w1m = exp2f(m - M);
                    const float w2m = exp2f(mo - M);
                    l = l * w1m + lo * w2m;
                    #pragma unroll
                    for (int d = 0; d < 8; ++d) acc8[d] = acc8[d] * w1m + ab[d] * w2m;
                    m = M;
                }
                const float inv = __builtin_amdgcn_rcpf(l);
                float vsel = acc8[0];
                #pragma unroll
                for (int d = 1; d < 8; ++d) vsel = (ks == d) ? acc8[d] : vsel;
                satt[wv][h * 8 + ks] = vsel * inv;
            }
            __syncthreads();   // SYNC_C

            // ---------- Wo compute: wave wv = d-slice [wv*8, wv*8+8) ----------
            {
                float acc[8];
                #pragma unroll
                for (int r = 0; r < 8; ++r) acc[r] = 0.f;
                #pragma unroll
                for (int i4 = 0; i4 < 2; ++i4) {
                    const int dd0 = wv * 8 + i4 * 4;
                    const float w0 = Wo[(dd0 + 0) * D_ + lane];
                    const float w1 = Wo[(dd0 + 1) * D_ + lane];
                    const float w2 = Wo[(dd0 + 2) * D_ + lane];
                    const float w3 = Wo[(dd0 + 3) * D_ + lane];
                    #pragma unroll
                    for (int r = 0; r < 8; ++r) {
                        const float4 s4 = *(const float4*)&satt[r][dd0];
                        acc[r] = fmaf(s4.x, w0, fmaf(s4.y, w1, fmaf(s4.z, w2, fmaf(s4.w, w3, acc[r]))));
                    }
                }
                #pragma unroll
                for (int r = 0; r < 8; ++r) U[(wv * 8 + r) * 64 + lane] = acc[r];
            }
            __syncthreads();   // SYNC_D

            // ---------- Wo combine ----------
            float so_reg;
            {
                float a = 0.f;
                #pragma unroll
                for (int w = 0; w < 8; ++w) a += U[(w * 8 + r_own) * 64 + c_own];
                so_reg = a + bo_r;
                sh[r_own][c_own] = stin + so_reg;
            }
            __syncthreads();   // SYNC_E

            // ---------- FFN1 compute: thread = (c2, d-half) ----------
            {
                const int c2 = tid & 255, p = tid >> 8;
                float acc[8];
                #pragma unroll
                for (int r = 0; r < 8; ++r) acc[r] = 0.f;
                #pragma unroll
                for (int i4 = 0; i4 < 8; ++i4) {
                    const int dd0 = p * 32 + i4 * 4;
                    const float w0 = W1[(dd0 + 0) * DFF_ + c2];
                    const float w1 = W1[(dd0 + 1) * DFF_ + c2];
                    const float w2 = W1[(dd0 + 2) * DFF_ + c2];
                    const float w3 = W1[(dd0 + 3) * DFF_ + c2];
                    #pragma unroll
                    for (int r = 0; r < 8; ++r) {
                        const float4 s4 = *(const float4*)&sh[r][dd0];
                        acc[r] = fmaf(s4.x, w0, fmaf(s4.y, w1, fmaf(s4.z, w2, fmaf(s4.w, w3, acc[r]))));
                    }
                }
                #pragma unroll
                for (int r = 0; r < 8; ++r) U[(p * 8 + r) * 256 + c2] = acc[r];
            }
            __syncthreads();   // SYNC_F

            // ---------- FFN1 combine ----------
            {
                const int c2 = tid & 255, rbase = (tid >> 8) * 4;
                #pragma unroll
                for (int i = 0; i < 4; ++i) {
                    const int r = rbase + i;
                    st[r][c2] = fmaxf(U[r * 256 + c2] + U[(8 + r) * 256 + c2] + b1_r, 0.f);
                }
            }
            __syncthreads();   // SYNC_G

            // ---------- FFN2 compute: wave wv = c2-slice [wv*32, wv*32+32) ----------
            {
                float acc[8];
                #pragma unroll
                for (int r = 0; r < 8; ++r) acc[r] = 0.f;
                #pragma unroll
                for (int i4 = 0; i4 < 8; ++i4) {
                    const int cc0 = wv * 32 + i4 * 4;
                    const float w0 = W2[(cc0 + 0) * D_ + lane];
                    const float w1 = W2[(cc0 + 1) * D_ + lane];
                    const float w2 = W2[(cc0 + 2) * D_ + lane];
                    const float w3 = W2[(cc0 + 3) * D_ + lane];
                    #pragma unroll
                    for (int r = 0; r < 8; ++r) {
                        const float4 s4 = *(const float4*)&st[r][cc0];
                        acc[r] = fmaf(s4.x, w0, fmaf(s4.y, w1, fmaf(s4.z, w2, fmaf(s4.w, w3, acc[r]))));
                    }
                }
                #pragma unroll
                for (int r = 0; r < 8; ++r) U[(wv * 8 + r) * 64 + lane] = acc[r];
            }
            __syncthreads();   // SYNC_H

            // ---------- FFN2 combine + k_i / y-update ----------
            {
                float f = 0.f;
                #pragma unroll
                for (int w = 0; w < 8; ++w) f += U[(w * 8 + r_own) * 64 + c_own];
                const float kv = so_reg + f + b2_r;
                if (stage < 5) {
                    kst[stage][r_own][c_own] = kv;
                } else {
                    float yn = B_tab[0] * kst[0][r_own][c_own];
                    yn = fmaf(B_tab[2], kst[2][r_own][c_own], yn);
                    yn = fmaf(B_tab[3], kst[3][r_own][c_own], yn);
                    yn = fmaf(B_tab[4], kst[4][r_own][c_own], yn);
                    yn = fmaf(B_tab[5], kv, yn);
                    yn = fmaf(DTs, yn, ys_reg);
                    if (step < NSTEPS - 1) ys_reg = yn;
                    else out[(row0 + r_own) * D_ + c_own] = yn;
                }
            }
            // next iteration's sy-write + SYNC_A orders everything needed
        }
    }
}

extern "C" void kernel_launch(void* const* d_in, const int* in_sizes, int n_in,
                              void* d_out, int out_size, void* d_ws, size_t ws_size,
                              hipStream_t stream) {
    const float* x  = (const float*)d_in[0];
    // d_in[1] = mask: broadcasts over the key axis -> softmax-invariant -> no-op.
    const float* Wq = (const float*)d_in[2];
    const float* bq = (const float*)d_in[3];
    const float* Wk = (const float*)d_in[4];
    const float* bk = (const float*)d_in[5];
    const float* Wv = (const float*)d_in[6];
    const float* bv = (const float*)d_in[7];
    const float* Wo = (const float*)d_in[8];
    const float* bo = (const float*)d_in[9];
    const float* W1 = (const float*)d_in[10];
    const float* b1 = (const float*)d_in[11];
    const float* W2 = (const float*)d_in[12];
    const float* b2 = (const float*)d_in[13];
    float* out  = (float*)d_out;

    float* base = (float*)d_ws;
    float* g_k  = base;                    // 2*N_*D_
    float* g_v  = g_k + 2 * N_ * D_;       // 2*N_*D_

    void* args[] = {
        (void*)&x,
        (void*)&Wq, (void*)&bq, (void*)&Wk, (void*)&bk,
        (void*)&Wv, (void*)&bv, (void*)&Wo, (void*)&bo,
        (void*)&W1, (void*)&b1, (void*)&W2, (void*)&b2,
        (void*)&out,
        (void*)&g_k, (void*)&g_v,
    };
    hipLaunchCooperativeKernel((void*)ode_enc_kernel, dim3(GWG), dim3(TPB),
                               args, 0, stream);
}

// Round 4
// 1402.250 us; speedup vs baseline: 1.3269x; 1.0466x over previous
//
#include <hip/hip_runtime.h>
#include <hip/hip_cooperative_groups.h>

namespace cg = cooperative_groups;

#define B_    4
#define S_    512
#define D_    64
#define DFF_  256
#define N_    2048          // B_*S_
#define GWG   256           // 1 block per CU (cooperative-safe)
#define TPB   512           // 8 waves/block = 2 waves/SIMD
#define RPW   8             // rows per workgroup
#define NSTEPS 4
#define DTs   0.25f

__constant__ float A_tab[6][5] = {
    {0.f, 0.f, 0.f, 0.f, 0.f},
    {0.25f, 0.f, 0.f, 0.f, 0.f},
    {3.0f/32.0f, 9.0f/32.0f, 0.f, 0.f, 0.f},
    {1932.0f/2197.0f, -7200.0f/2197.0f, 7296.0f/2197.0f, 0.f, 0.f},
    {439.0f/216.0f, -8.0f, 3680.0f/513.0f, -845.0f/4104.0f, 0.f},
    {-8.0f/27.0f, 2.0f, -3544.0f/2565.0f, 1859.0f/4104.0f, -11.0f/40.0f}};
__constant__ float B_tab[6] = {16.0f/135.0f, 0.0f, 6656.0f/12825.0f,
                               28561.0f/56430.0f, -9.0f/50.0f, 2.0f/55.0f};

__global__ __launch_bounds__(TPB, 1) void ode_enc_kernel(
    const float* __restrict__ x,
    const float* __restrict__ Wq, const float* __restrict__ bq,
    const float* __restrict__ Wk, const float* __restrict__ bk,
    const float* __restrict__ Wv, const float* __restrict__ bv,
    const float* __restrict__ Wo, const float* __restrict__ bo,
    const float* __restrict__ W1, const float* __restrict__ b1,
    const float* __restrict__ W2, const float* __restrict__ b2,
    float* __restrict__ out,
    float* __restrict__ g_k,    // [2][N_*D_] ping-pong K
    float* __restrict__ g_v)    // [2][N_*D_] ping-pong V
{
    cg::grid_group grid = cg::this_grid();
    const int wg   = blockIdx.x;
    const int tid  = threadIdx.x;
    const int lane = tid & 63;
    const int wv   = tid >> 6;            // wave id 0..7
    // XCD-aware swizzle: consecutive sid chunks of 32 land on one XCD
    // (XCD = wg % 8 round-robin assumption) -> each XCD serves ONE batch.
    const int sid  = (wg & 7) * 32 + (wg >> 3);
    const int row0  = sid * RPW;
    const int krow0 = (sid >> 6) * S_;    // batch base (64 sids per batch)

    const int r_own = wv;                 // this thread's (row, col) element
    const int c_own = lane;

    __shared__ float sy[RPW][D_];         // stage input
    __shared__ float satt[RPW][D_];       // attention output
    __shared__ float sh[RPW][D_];         // FFN input
    __shared__ float st[RPW][DFF_];       // relu(h@W1+b1)
    __shared__ float kst[5][RPW][D_];     // RK slopes (same-thread access only)
    __shared__ float U[4096];             // partials union (16 KB)

    float ys_reg = x[(row0 + r_own) * D_ + c_own];
    const float bq_r = bq[c_own], bk_r = bk[c_own], bv_r = bv[c_own];
    const float bo_r = bo[c_own], b2_r = b2[c_own];
    const float b1_r = b1[tid & 255];

    for (int step = 0; step < NSTEPS; ++step) {
        for (int stage = 0; stage < 6; ++stage) {
            const int buf = (step * 6 + stage) & 1;

            // ---------- P1: RK stage input ----------
            float stin = ys_reg;
            #pragma unroll
            for (int j = 0; j < 5; ++j)
                if (j < stage) stin = fmaf(DTs * A_tab[stage][j], kst[j][r_own][c_own], stin);
            sy[r_own][c_own] = stin;
            __syncthreads();   // SYNC_A

            // ---------- QKV compute: waves 0..5 = (mat, d-half) ----------
            if (wv < 6) {
                const int mat = wv >> 1, p = wv & 1;
                const float* Wm = (mat == 0) ? Wq : (mat == 1) ? Wk : Wv;
                float acc[8];
                #pragma unroll
                for (int r = 0; r < 8; ++r) acc[r] = 0.f;
                #pragma unroll
                for (int i4 = 0; i4 < 8; ++i4) {
                    const int dd0 = p * 32 + i4 * 4;
                    const float w0 = Wm[(dd0 + 0) * D_ + lane];
                    const float w1 = Wm[(dd0 + 1) * D_ + lane];
                    const float w2 = Wm[(dd0 + 2) * D_ + lane];
                    const float w3 = Wm[(dd0 + 3) * D_ + lane];
                    #pragma unroll
                    for (int r = 0; r < 8; ++r) {
                        const float4 s4 = *(const float4*)&sy[r][dd0];
                        acc[r] = fmaf(s4.x, w0, fmaf(s4.y, w1, fmaf(s4.z, w2, fmaf(s4.w, w3, acc[r]))));
                    }
                }
                #pragma unroll
                for (int r = 0; r < 8; ++r) U[(wv * 8 + r) * 64 + lane] = acc[r];
            }
            __syncthreads();   // SYNC_B

            // ---------- QKV combine ----------
            float sqreg;
            {
                const float qv = U[(0 * 8 + r_own) * 64 + c_own] + U[(1 * 8 + r_own) * 64 + c_own] + bq_r;
                const float kv = U[(2 * 8 + r_own) * 64 + c_own] + U[(3 * 8 + r_own) * 64 + c_own] + bk_r;
                const float vv = U[(4 * 8 + r_own) * 64 + c_own] + U[(5 * 8 + r_own) * 64 + c_own] + bv_r;
                sqreg = qv;
                const size_t kidx = ((size_t)buf * N_ + row0 + r_own) * D_ + c_own;
                g_k[kidx] = kv;
                g_v[kidx] = vv;
            }
            grid.sync();       // K/V of the whole batch visible

            // ---------- attention: wave wv = q-row wv, direct L2 reads ----------
            {
                const int h  = lane & 7;       // head
                const int ks = lane >> 3;      // 64-key slice
                const float SC = 0.51006702f;  // log2(e)/sqrt(8)
                float qv[8];
                #pragma unroll
                for (int d = 0; d < 8; ++d) qv[d] = __shfl(sqreg, h * 8 + d) * SC;

                const float* kb = g_k + ((size_t)buf * N_ + krow0 + ks * 64) * D_ + h * 8;
                const float* vb = g_v + ((size_t)buf * N_ + krow0 + ks * 64) * D_ + h * 8;

                float m = -1e30f, l = 0.f;
                float acc8[8];
                #pragma unroll
                for (int d = 0; d < 8; ++d) acc8[d] = 0.f;

                for (int j0 = 0; j0 < 64; j0 += 8) {
                    float4 kd[8][2], vd[8][2];
                    #pragma unroll
                    for (int u = 0; u < 8; ++u) {   // 16 K-loads in flight
                        const float* kr = kb + (size_t)(j0 + u) * D_;
                        kd[u][0] = *(const float4*)kr;
                        kd[u][1] = *(const float4*)(kr + 4);
                    }
                    #pragma unroll
                    for (int u = 0; u < 8; ++u) {   // 16 V-loads in flight
                        const float* vr = vb + (size_t)(j0 + u) * D_;
                        vd[u][0] = *(const float4*)vr;
                        vd[u][1] = *(const float4*)(vr + 4);
                    }
                    #pragma unroll
                    for (int u = 0; u < 8; ++u) {
                        const float4 ka = kd[u][0], kb2 = kd[u][1];
                        float s = fmaf(qv[0],ka.x,fmaf(qv[1],ka.y,fmaf(qv[2],ka.z,fmaf(qv[3],ka.w,
                                  fmaf(qv[4],kb2.x,fmaf(qv[5],kb2.y,fmaf(qv[6],kb2.z,qv[7]*kb2.w)))))));
                        if (s > m + 8.f) {          // deferred-rescale (T13)
                            const float al = exp2f(m - s);
                            m = s; l *= al;
                            #pragma unroll
                            for (int d = 0; d < 8; ++d) acc8[d] *= al;
                        }
                        const float p = exp2f(s - m);
                        l += p;
                        const float4 va = vd[u][0], vb2 = vd[u][1];
                        acc8[0] = fmaf(p, va.x,  acc8[0]);
                        acc8[1] = fmaf(p, va.y,  acc8[1]);
                        acc8[2] = fmaf(p, va.z,  acc8[2]);
                        acc8[3] = fmaf(p, va.w,  acc8[3]);
                        acc8[4] = fmaf(p, vb2.x, acc8[4]);
                        acc8[5] = fmaf(p, vb2.y, acc8[5]);
                        acc8[6] = fmaf(p, vb2.z, acc8[6]);
                        acc8[7] = fmaf(p, vb2.w, acc8[7]);
                    }
                }

                // merge across ks (lane bits 3..5 -> offsets 8,16,32)
                #pragma unroll
                for (int off = 8; off < 64; off <<= 1) {
                    const float mo = __shfl_xor(m, off);
                    const float lo = __shfl_xor(l, off);
                    float ab[8];
                    #pragma unroll
                    for (int d = 0; d < 8; ++d) ab[d] = __shfl_xor(acc8[d], off);
                    const float M  = fmaxf(m, mo);
                    const float w1m = exp2f(m - M);
                    const float w2m = exp2f(mo - M);
                    l = l * w1m + lo * w2m;
                    #pragma unroll
                    for (int d = 0; d < 8; ++d) acc8[d] = acc8[d] * w1m + ab[d] * w2m;
                    m = M;
                }
                const float inv = __builtin_amdgcn_rcpf(l);
                float vsel = acc8[0];
                #pragma unroll
                for (int d = 1; d < 8; ++d) vsel = (ks == d) ? acc8[d] : vsel;
                satt[wv][h * 8 + ks] = vsel * inv;
            }
            __syncthreads();   // SYNC_C

            // ---------- Wo compute: wave wv = d-slice ----------
            {
                float acc[8];
                #pragma unroll
                for (int r = 0; r < 8; ++r) acc[r] = 0.f;
                #pragma unroll
                for (int i4 = 0; i4 < 2; ++i4) {
                    const int dd0 = wv * 8 + i4 * 4;
                    const float w0 = Wo[(dd0 + 0) * D_ + lane];
                    const float w1 = Wo[(dd0 + 1) * D_ + lane];
                    const float w2 = Wo[(dd0 + 2) * D_ + lane];
                    const float w3 = Wo[(dd0 + 3) * D_ + lane];
                    #pragma unroll
                    for (int r = 0; r < 8; ++r) {
                        const float4 s4 = *(const float4*)&satt[r][dd0];
                        acc[r] = fmaf(s4.x, w0, fmaf(s4.y, w1, fmaf(s4.z, w2, fmaf(s4.w, w3, acc[r]))));
                    }
                }
                #pragma unroll
                for (int r = 0; r < 8; ++r) U[(wv * 8 + r) * 64 + lane] = acc[r];
            }
            __syncthreads();   // SYNC_D

            // ---------- Wo combine ----------
            float so_reg;
            {
                float a = 0.f;
                #pragma unroll
                for (int w = 0; w < 8; ++w) a += U[(w * 8 + r_own) * 64 + c_own];
                so_reg = a + bo_r;
                sh[r_own][c_own] = stin + so_reg;
            }
            __syncthreads();   // SYNC_E

            // ---------- FFN1 compute: thread = (c2, d-half) ----------
            {
                const int c2 = tid & 255, p = tid >> 8;
                float acc[8];
                #pragma unroll
                for (int r = 0; r < 8; ++r) acc[r] = 0.f;
                #pragma unroll
                for (int i4 = 0; i4 < 8; ++i4) {
                    const int dd0 = p * 32 + i4 * 4;
                    const float w0 = W1[(dd0 + 0) * DFF_ + c2];
                    const float w1 = W1[(dd0 + 1) * DFF_ + c2];
                    const float w2 = W1[(dd0 + 2) * DFF_ + c2];
                    const float w3 = W1[(dd0 + 3) * DFF_ + c2];
                    #pragma unroll
                    for (int r = 0; r < 8; ++r) {
                        const float4 s4 = *(const float4*)&sh[r][dd0];
                        acc[r] = fmaf(s4.x, w0, fmaf(s4.y, w1, fmaf(s4.z, w2, fmaf(s4.w, w3, acc[r]))));
                    }
                }
                #pragma unroll
                for (int r = 0; r < 8; ++r) U[(p * 8 + r) * 256 + c2] = acc[r];
            }
            __syncthreads();   // SYNC_F

            // ---------- FFN1 combine ----------
            {
                const int c2 = tid & 255, rbase = (tid >> 8) * 4;
                #pragma unroll
                for (int i = 0; i < 4; ++i) {
                    const int r = rbase + i;
                    st[r][c2] = fmaxf(U[r * 256 + c2] + U[(8 + r) * 256 + c2] + b1_r, 0.f);
                }
            }
            __syncthreads();   // SYNC_G

            // ---------- FFN2 compute: wave wv = c2-slice ----------
            {
                float acc[8];
                #pragma unroll
                for (int r = 0; r < 8; ++r) acc[r] = 0.f;
                #pragma unroll
                for (int i4 = 0; i4 < 8; ++i4) {
                    const int cc0 = wv * 32 + i4 * 4;
                    const float w0 = W2[(cc0 + 0) * D_ + lane];
                    const float w1 = W2[(cc0 + 1) * D_ + lane];
                    const float w2 = W2[(cc0 + 2) * D_ + lane];
                    const float w3 = W2[(cc0 + 3) * D_ + lane];
                    #pragma unroll
                    for (int r = 0; r < 8; ++r) {
                        const float4 s4 = *(const float4*)&st[r][cc0];
                        acc[r] = fmaf(s4.x, w0, fmaf(s4.y, w1, fmaf(s4.z, w2, fmaf(s4.w, w3, acc[r]))));
                    }
                }
                #pragma unroll
                for (int r = 0; r < 8; ++r) U[(wv * 8 + r) * 64 + lane] = acc[r];
            }
            __syncthreads();   // SYNC_H

            // ---------- FFN2 combine + k_i / y-update ----------
            {
                float f = 0.f;
                #pragma unroll
                for (int w = 0; w < 8; ++w) f += U[(w * 8 + r_own) * 64 + c_own];
                const float kv = so_reg + f + b2_r;
                if (stage < 5) {
                    kst[stage][r_own][c_own] = kv;
                } else {
                    float yn = B_tab[0] * kst[0][r_own][c_own];
                    yn = fmaf(B_tab[2], kst[2][r_own][c_own], yn);
                    yn = fmaf(B_tab[3], kst[3][r_own][c_own], yn);
                    yn = fmaf(B_tab[4], kst[4][r_own][c_own], yn);
                    yn = fmaf(B_tab[5], kv, yn);
                    yn = fmaf(DTs, yn, ys_reg);
                    if (step < NSTEPS - 1) ys_reg = yn;
                    else out[(row0 + r_own) * D_ + c_own] = yn;
                }
            }
            // next stage's SYNC_A orders U reuse; kst is same-thread.
        }
    }
}

extern "C" void kernel_launch(void* const* d_in, const int* in_sizes, int n_in,
                              void* d_out, int out_size, void* d_ws, size_t ws_size,
                              hipStream_t stream) {
    const float* x  = (const float*)d_in[0];
    // d_in[1] = mask: broadcasts over the key axis -> softmax-invariant -> no-op.
    const float* Wq = (const float*)d_in[2];
    const float* bq = (const float*)d_in[3];
    const float* Wk = (const float*)d_in[4];
    const float* bk = (const float*)d_in[5];
    const float* Wv = (const float*)d_in[6];
    const float* bv = (const float*)d_in[7];
    const float* Wo = (const float*)d_in[8];
    const float* bo = (const float*)d_in[9];
    const float* W1 = (const float*)d_in[10];
    const float* b1 = (const float*)d_in[11];
    const float* W2 = (const float*)d_in[12];
    const float* b2 = (const float*)d_in[13];
    float* out  = (float*)d_out;

    float* base = (float*)d_ws;
    float* g_k  = base;                    // 2*N_*D_
    float* g_v  = g_k + 2 * N_ * D_;       // 2*N_*D_

    void* args[] = {
        (void*)&x,
        (void*)&Wq, (void*)&bq, (void*)&Wk, (void*)&bk,
        (void*)&Wv, (void*)&bv, (void*)&Wo, (void*)&bo,
        (void*)&W1, (void*)&b1, (void*)&W2, (void*)&b2,
        (void*)&out,
        (void*)&g_k, (void*)&g_v,
    };
    hipLaunchCooperativeKernel((void*)ode_enc_kernel, dim3(GWG), dim3(TPB),
                               args, 0, stream);
}